// Round 5
// baseline (823.365 us; speedup 1.0000x reference)
//
#include <hip/hip_runtime.h>
#include <cstdint>
#include <cstddef>

// Problem dims (fixed)
#define T_TOKENS 8192
#define H_DIM    1024
#define F_DIM    4096
#define E_NUM    8

typedef __bf16 bf16x8 __attribute__((ext_vector_type(8)));
typedef float  f32x4  __attribute__((ext_vector_type(4)));
typedef unsigned short ushort8 __attribute__((ext_vector_type(8)));

#define AS_GLOBAL(p) ((const __attribute__((address_space(1))) void*)(p))
#define AS_LDS(p)    ((__attribute__((address_space(3))) void*)(p))

__device__ inline unsigned short f2b(float f) {
  unsigned int u = __float_as_uint(f);
  unsigned int r = (u + 0x7fffu + ((u >> 16) & 1u)) >> 16;   // RNE
  return (unsigned short)r;
}
__device__ inline float b2f(unsigned short u) {
  return __uint_as_float(((unsigned int)u) << 16);
}
// gelu(v) = 0.5 v (1 + tanh(u)) = v * sigmoid(2u), u = 0.79788456(v + 0.044715 v^3)
__device__ inline float gelu_fast(float v) {
  float u2 = 1.5957691216057308f * v * (1.0f + 0.044715f * v * v);
  return v / (1.0f + __expf(-u2));
}

// ---------------------------------------------------------------------------
// Transpose + fp32->bf16 cast:  in [E][R][C] fp32  ->  out [E][C][R] bf16
// Also zeroes the 24-word routing meta block when zc != nullptr.
// ---------------------------------------------------------------------------
__global__ __launch_bounds__(256) void transpose_cast_kernel(
    const float* __restrict__ in, unsigned short* __restrict__ out, int R, int C,
    int* __restrict__ zc)
{
  __shared__ float tile[64][65];
  const int tid = threadIdx.x;
  if (zc && blockIdx.x == 0 && blockIdx.y == 0 && blockIdx.z == 0 && tid < 24)
    zc[tid] = 0;
  const int e  = blockIdx.z;
  const int c0 = blockIdx.x * 64;
  const int r0 = blockIdx.y * 64;
  const float* src = in + (size_t)e * R * C;
  unsigned short* dst = out + (size_t)e * R * C;
  const int rl  = tid >> 4;
  const int cl4 = (tid & 15) * 4;
#pragma unroll
  for (int i = 0; i < 4; ++i) {
    float4 v = *(const float4*)(src + (size_t)(r0 + rl + i * 16) * C + c0 + cl4);
    tile[rl + i * 16][cl4 + 0] = v.x;
    tile[rl + i * 16][cl4 + 1] = v.y;
    tile[rl + i * 16][cl4 + 2] = v.z;
    tile[rl + i * 16][cl4 + 3] = v.w;
  }
  __syncthreads();
#pragma unroll
  for (int itw = 0; itw < 2; ++itw) {
    int g  = itw * 256 + tid;       // 512 items: 64 dst rows x 8 chunks
    int c  = g >> 3;                // dst row (source column)
    int rc = g & 7;                 // 8-element chunk along source rows
    ushort8 u;
#pragma unroll
    for (int k = 0; k < 8; ++k) u[k] = f2b(tile[rc * 8 + k][c]);
    *(ushort8*)(dst + (size_t)(c0 + c) * R + r0 + rc * 8) = u;
  }
}

// ---------------------------------------------------------------------------
// Router: logits (fp32) -> softmax -> top-2; casts x to bf16; block-aggregated
// expert counts -> global atomics.
// ---------------------------------------------------------------------------
__global__ __launch_bounds__(256) void router_kernel(
    const float* __restrict__ x, const float* __restrict__ rw,
    unsigned short* __restrict__ xb, int* __restrict__ top_e, float* __restrict__ top_p,
    int* __restrict__ counts)
{
  __shared__ float lrw[H_DIM * 9];   // padded stride 9 to spread banks
  __shared__ int lc[E_NUM];
  const int tid = threadIdx.x;
  if (tid < E_NUM) lc[tid] = 0;
  for (int r = tid; r < H_DIM; r += 256) {
    const float* s = rw + r * 8;
    float4 a = *(const float4*)(s);
    float4 b = *(const float4*)(s + 4);
    float* d = &lrw[r * 9];
    d[0] = a.x; d[1] = a.y; d[2] = a.z; d[3] = a.w;
    d[4] = b.x; d[5] = b.y; d[6] = b.z; d[7] = b.w;
  }
  __syncthreads();
  const int lane = tid & 63, wid = tid >> 6;
  for (int i = 0; i < 8; ++i) {
    const int t = blockIdx.x * 32 + wid * 8 + i;
    float acc[8] = {0.f, 0.f, 0.f, 0.f, 0.f, 0.f, 0.f, 0.f};
    const float* xrow = x + (size_t)t * H_DIM;
    unsigned short* xbrow = xb + (size_t)t * H_DIM;
#pragma unroll
    for (int j = 0; j < 16; ++j) {
      int h = j * 64 + lane;
      float xv = xrow[h];
      xbrow[h] = f2b(xv);
      const float* rr = &lrw[h * 9];
#pragma unroll
      for (int e = 0; e < 8; ++e) acc[e] += xv * rr[e];
    }
#pragma unroll
    for (int e = 0; e < 8; ++e) {
#pragma unroll
      for (int s = 32; s > 0; s >>= 1) acc[e] += __shfl_xor(acc[e], s, 64);
    }
    if (lane == 0) {
      float mx = acc[0];
      for (int e = 1; e < 8; ++e) mx = fmaxf(mx, acc[e]);
      float p[8]; float sum = 0.f;
      for (int e = 0; e < 8; ++e) { p[e] = expf(acc[e] - mx); sum += p[e]; }
      float inv = 1.0f / sum;
      int i1 = 0; float b1 = p[0];
      for (int e = 1; e < 8; ++e) if (p[e] > b1) { b1 = p[e]; i1 = e; }
      int i2 = (i1 == 0) ? 1 : 0; float b2 = p[i2];
      for (int e = 0; e < 8; ++e) if (e != i1 && p[e] > b2) { b2 = p[e]; i2 = e; }
      top_e[2 * t]     = i1; top_p[2 * t]     = b1 * inv;
      top_e[2 * t + 1] = i2; top_p[2 * t + 1] = b2 * inv;
      atomicAdd(&lc[i1], 1);
      atomicAdd(&lc[i2], 1);
    }
  }
  __syncthreads();
  if (tid < E_NUM) atomicAdd(&counts[tid], lc[tid]);
}

// ---------------------------------------------------------------------------
// Dispatch: assign each (token, k) a slot in its expert's contiguous segment.
// ---------------------------------------------------------------------------
__global__ __launch_bounds__(256) void assign_kernel(
    const int* __restrict__ top_e, const float* __restrict__ top_p,
    const int* __restrict__ counts, int* __restrict__ cursor,
    int* __restrict__ map, float* __restrict__ gate, int* __restrict__ slot_of,
    int* __restrict__ offsets)
{
  __shared__ int lc[E_NUM], lb[E_NUM], loff[E_NUM];
  const int tid = threadIdx.x;
  const int t = blockIdx.x * 256 + tid;
  if (tid < E_NUM) lc[tid] = 0;
  if (tid == 0) {
    int o = 0;
    for (int e = 0; e < E_NUM; ++e) { loff[e] = o; o += counts[e]; }
  }
  __syncthreads();
  int e0 = top_e[2 * t], e1 = top_e[2 * t + 1];
  int p0 = atomicAdd(&lc[e0], 1);
  int p1 = atomicAdd(&lc[e1], 1);
  __syncthreads();
  if (tid < E_NUM) lb[tid] = atomicAdd(&cursor[tid], lc[tid]);
  __syncthreads();
  int s0 = loff[e0] + lb[e0] + p0;
  int s1 = loff[e1] + lb[e1] + p1;
  map[s0] = t; gate[s0] = top_p[2 * t];
  map[s1] = t; gate[s1] = top_p[2 * t + 1];
  slot_of[2 * t] = s0; slot_of[2 * t + 1] = s1;
  if (blockIdx.x == 0 && tid < E_NUM) offsets[tid] = loff[tid];
}

// ---------------------------------------------------------------------------
// 256x256 grouped GEMM, staging-BW-aware schedule.
// BK=64, 512 thr = 8 waves (2M x 4N), wave-tile 128x64, acc[8][4].
// LDS 128 KB = 8 x 16KB half-K units: A ring slots [0,32768), B [32768,65536),
// unit(k,h) -> slot (2k+h)&3. Units u=4k+c staged 1/phase (2 gload_lds),
// consumed u=4k..4k+3 during K-tile k's 4 phases:
//   ph1: bF(kh0)+aF(kh0,mi0-3); stage A(k+1,h1); 16 MFMA; bar
//   ph2: aF(kh0,mi4-7);         stage B(k+1,h1); 16 MFMA; bar
//   ph3: bF(kh1)+aF(kh1,mi0-3); stage A(k+2,h0); 16 MFMA; bar
//   ph4: aF(kh1,mi4-7);         stage B(k+2,h0); 16 MFMA; vmcnt(4); bar
// Per-wave vmcnt(4) at each K-tile boundary => units <= 4k+7 landed (next
// K-tile fully resident; 2 units stay in flight -- never drained mid-loop).
// Every WAR (stage overwriting slot (2k+4)&3 etc.) is >=1 barrier after that
// slot's last read. K-chunk swizzle chunk^=row&3 on stage-source AND read
// spreads the 64-B rows across all banks (floor occupancy, no conflicts).
// ---------------------------------------------------------------------------
template <int KD, int ND, bool USE_MAP, bool GELU>
__global__ __launch_bounds__(512, 2) void moe_gemm256_kernel(
    const unsigned short* __restrict__ A, const unsigned short* __restrict__ Bt,
    const int* __restrict__ map, const float* __restrict__ gate,
    const int* __restrict__ counts, const int* __restrict__ offsets,
    unsigned short* __restrict__ C)
{
  __shared__ unsigned short ls[65536];   // 128 KB
  const int e   = blockIdx.x;
  const int cnt = counts[e];
  const int tile_m = blockIdx.y;
  if (tile_m * 256 >= cnt) return;
  const int off    = offsets[e];
  const int tile_n = blockIdx.z;
  const int tid    = threadIdx.x;       // 0..511

  // ---- staging sources: thread covers chunk g=tid (row tid>>2) and
  // g=512+tid (row +128); phys chunk kcp=tid&3 holds logical kcl=kcp^(row&3).
  const int row_lo = tid >> 2;                       // 0..127
  const int kcl8 = (((tid & 3) ^ (row_lo & 3)) * 8); // swizzled src chunk (shorts)
  int rm0 = tile_m * 256 + row_lo;        if (rm0 > cnt - 1) rm0 = cnt - 1;
  int rm1 = tile_m * 256 + row_lo + 128;  if (rm1 > cnt - 1) rm1 = cnt - 1;
  const int ar0 = USE_MAP ? map[off + rm0] : (off + rm0);
  const int ar1 = USE_MAP ? map[off + rm1] : (off + rm1);
  const unsigned short* aP0 = A + (size_t)ar0 * KD + kcl8;
  const unsigned short* aP1 = A + (size_t)ar1 * KD + kcl8;
  const unsigned short* bBase = Bt + (size_t)e * ND * KD;
  const unsigned short* bP0 = bBase + (size_t)(tile_n * 256 + row_lo) * KD + kcl8;
  const unsigned short* bP1 = bBase + (size_t)(tile_n * 256 + row_lo + 128) * KD + kcl8;

  auto STAGE_A = [&](int k, int h) {
    const int ko = k * 64 + h * 32;
    const int sl = (2 * k + h) & 3;
    __builtin_amdgcn_global_load_lds(AS_GLOBAL(aP0 + ko),
        AS_LDS(ls + sl * 8192 + tid * 8), 16, 0, 0);
    __builtin_amdgcn_global_load_lds(AS_GLOBAL(aP1 + ko),
        AS_LDS(ls + sl * 8192 + (512 + tid) * 8), 16, 0, 0);
  };
  auto STAGE_B = [&](int k, int h) {
    const int ko = k * 64 + h * 32;
    const int sl = (2 * k + h) & 3;
    __builtin_amdgcn_global_load_lds(AS_GLOBAL(bP0 + ko),
        AS_LDS(ls + 32768 + sl * 8192 + tid * 8), 16, 0, 0);
    __builtin_amdgcn_global_load_lds(AS_GLOBAL(bP1 + ko),
        AS_LDS(ls + 32768 + sl * 8192 + (512 + tid) * 8), 16, 0, 0);
  };

  const int lane = tid & 63;
  const int wid  = tid >> 6;
  const int wm = wid >> 2, wn = wid & 3;          // 2x4 wave grid, 128x64 each
  const int lr = lane & 15, kg = lane >> 4;
  const int kx8 = ((kg ^ (lr & 3)) * 8);          // de-swizzled read chunk
  const int aRd = (wm * 128 + lr) * 32 + kx8;     // row&3 == lr&3 (offsets %4==0)
  const int bRd = (wn * 64  + lr) * 32 + kx8;

  f32x4 acc[8][4];
#pragma unroll
  for (int mi = 0; mi < 8; ++mi)
#pragma unroll
    for (int ni = 0; ni < 4; ++ni) acc[mi][ni] = (f32x4){0.f, 0.f, 0.f, 0.f};

  constexpr int NK = KD / 64;

  // prologue: units 0..5 (K-tile 0 complete + kh0 of K-tile 1)
  STAGE_A(0, 0); STAGE_B(0, 0); STAGE_A(0, 1); STAGE_B(0, 1);
  STAGE_A(1, 0); STAGE_B(1, 0);
  asm volatile("s_waitcnt vmcnt(4)" ::: "memory");   // units 0..3 landed
  asm volatile("s_barrier" ::: "memory");

#pragma unroll 1
  for (int k = 0; k < NK; ++k) {
    const unsigned short* pA0 = ls + (((2 * k) & 3) * 8192) + aRd;
    const unsigned short* pB0 = ls + 32768 + (((2 * k) & 3) * 8192) + bRd;
    const unsigned short* pA1 = ls + (((2 * k + 1) & 3) * 8192) + aRd;
    const unsigned short* pB1 = ls + 32768 + (((2 * k + 1) & 3) * 8192) + bRd;
    bf16x8 aF[4], bF[4];

    // ---- phase 1: ks=0, mi 0-3 (+ B ks=0 frags, reused in phase 2) ----
#pragma unroll
    for (int ni = 0; ni < 4; ++ni) bF[ni] = *(const bf16x8*)(pB0 + ni * 512);
#pragma unroll
    for (int j = 0; j < 4; ++j)    aF[j]  = *(const bf16x8*)(pA0 + j * 512);
    if (k + 1 < NK) STAGE_A(k + 1, 1);
    __builtin_amdgcn_s_setprio(1);
#pragma unroll
    for (int j = 0; j < 4; ++j)
#pragma unroll
      for (int ni = 0; ni < 4; ++ni)
        acc[j][ni] = __builtin_amdgcn_mfma_f32_16x16x32_bf16(aF[j], bF[ni], acc[j][ni], 0, 0, 0);
    __builtin_amdgcn_s_setprio(0);
    asm volatile("s_barrier" ::: "memory");

    // ---- phase 2: ks=0, mi 4-7 (reuse bF) ----
#pragma unroll
    for (int j = 0; j < 4; ++j)    aF[j] = *(const bf16x8*)(pA0 + (4 + j) * 512);
    if (k + 1 < NK) STAGE_B(k + 1, 1);
    __builtin_amdgcn_s_setprio(1);
#pragma unroll
    for (int j = 0; j < 4; ++j)
#pragma unroll
      for (int ni = 0; ni < 4; ++ni)
        acc[4 + j][ni] = __builtin_amdgcn_mfma_f32_16x16x32_bf16(aF[j], bF[ni], acc[4 + j][ni], 0, 0, 0);
    __builtin_amdgcn_s_setprio(0);
    asm volatile("s_barrier" ::: "memory");

    // ---- phase 3: ks=1, mi 0-3 (+ B ks=1 frags) ----
#pragma unroll
    for (int ni = 0; ni < 4; ++ni) bF[ni] = *(const bf16x8*)(pB1 + ni * 512);
#pragma unroll
    for (int j = 0; j < 4; ++j)    aF[j]  = *(const bf16x8*)(pA1 + j * 512);
    if (k + 2 < NK) STAGE_A(k + 2, 0);
    __builtin_amdgcn_s_setprio(1);
#pragma unroll
    for (int j = 0; j < 4; ++j)
#pragma unroll
      for (int ni = 0; ni < 4; ++ni)
        acc[j][ni] = __builtin_amdgcn_mfma_f32_16x16x32_bf16(aF[j], bF[ni], acc[j][ni], 0, 0, 0);
    __builtin_amdgcn_s_setprio(0);
    asm volatile("s_barrier" ::: "memory");

    // ---- phase 4: ks=1, mi 4-7; counted boundary wait ----
#pragma unroll
    for (int j = 0; j < 4; ++j)    aF[j] = *(const bf16x8*)(pA1 + (4 + j) * 512);
    if (k + 2 < NK) STAGE_B(k + 2, 0);
    __builtin_amdgcn_s_setprio(1);
#pragma unroll
    for (int j = 0; j < 4; ++j)
#pragma unroll
      for (int ni = 0; ni < 4; ++ni)
        acc[4 + j][ni] = __builtin_amdgcn_mfma_f32_16x16x32_bf16(aF[j], bF[ni], acc[4 + j][ni], 0, 0, 0);
    __builtin_amdgcn_s_setprio(0);
    if (k >= NK - 2) {
      asm volatile("s_waitcnt vmcnt(0)" ::: "memory");   // tail drain
    } else {
      asm volatile("s_waitcnt vmcnt(4)" ::: "memory");   // next K-tile resident
    }
    asm volatile("s_barrier" ::: "memory");
  }

  // ---- Epilogue: activation/gate -> LDS repack (2 row-half passes) ----
  __syncthreads();
#pragma unroll
  for (int h = 0; h < 2; ++h) {
    if (h) __syncthreads();                 // store pass h-1 done before overwrite
    if (wm == h) {
#pragma unroll
      for (int mi = 0; mi < 8; ++mi) {
#pragma unroll
        for (int r = 0; r < 4; ++r) {
          int Rl = mi * 16 + kg * 4 + r;    // 0..127 within the half
          float gv = 1.0f;
          if (!GELU) {
            int gm = tile_m * 256 + h * 128 + Rl;
            int gmc = gm < cnt ? gm : cnt - 1;
            gv = gate[off + gmc];
          }
#pragma unroll
          for (int ni = 0; ni < 4; ++ni) {
            int col = wn * 64 + ni * 16 + lr;
            float v = acc[mi][ni][r];
            v = GELU ? gelu_fast(v) : v * gv;
            ls[Rl * 264 + col] = f2b(v);
          }
        }
      }
    }
    __syncthreads();
#pragma unroll
    for (int it = 0; it < 8; ++it) {
      int g = it * 512 + tid;               // 128 rows x 32 chunks of 8
      int R = g >> 5, c8 = g & 31;
      int gm = tile_m * 256 + h * 128 + R;
      if (gm < cnt) {
        ushort8 v = *(const ushort8*)(ls + R * 264 + c8 * 8);
        *(ushort8*)(C + (size_t)(off + gm) * ND + tile_n * 256 + c8 * 8) = v;
      }
    }
  }
}

// ---------------------------------------------------------------------------
// Combine: out[t] = y[slot0(t)] + y[slot1(t)]   (gates already applied)
// ---------------------------------------------------------------------------
__global__ __launch_bounds__(256) void combine_kernel(
    const unsigned short* __restrict__ y, const int* __restrict__ slot_of,
    float* __restrict__ out)
{
  const int t  = blockIdx.x;
  const int h0 = threadIdx.x * 4;
  const int s0 = slot_of[2 * t], s1 = slot_of[2 * t + 1];
  ushort4 a = *(const ushort4*)(y + (size_t)s0 * H_DIM + h0);
  ushort4 b = *(const ushort4*)(y + (size_t)s1 * H_DIM + h0);
  float4 o;
  o.x = b2f(a.x) + b2f(b.x);
  o.y = b2f(a.y) + b2f(b.y);
  o.z = b2f(a.z) + b2f(b.z);
  o.w = b2f(a.w) + b2f(b.w);
  *(float4*)(out + (size_t)t * H_DIM + h0) = o;
}

// ---------------------------------------------------------------------------
extern "C" void kernel_launch(void* const* d_in, const int* in_sizes, int n_in,
                              void* d_out, int out_size, void* d_ws, size_t ws_size,
                              hipStream_t stream) {
  const float* x  = (const float*)d_in[0];   // [S,B,H] = [8192,1024]
  const float* rw = (const float*)d_in[1];   // [H,E]   = [1024,8]
  const float* w1 = (const float*)d_in[2];   // [E,H,F]
  const float* w2 = (const float*)d_in[3];   // [E,F,H]
  float* out = (float*)d_out;

  char* ws = (char*)d_ws;
  unsigned short* wT     = (unsigned short*)ws;                     // 64 MB (w1t, then w2t)
  unsigned short* xb     = (unsigned short*)(ws + (64ull  << 20));  // 16 MB
  unsigned short* y      = (unsigned short*)(ws + (64ull  << 20));  // 32 MB (reuses dead xb)
  unsigned short* hidden = (unsigned short*)(ws + (96ull  << 20));  // 128 MB
  char* meta = ws + (224ull << 20);
  int*   top_e   = (int*)meta;                     // 16384
  float* top_p   = (float*)(meta + (64 << 10));    // 16384
  int*   map     = (int*)(meta + (128 << 10));     // 16384
  float* gate    = (float*)(meta + (192 << 10));   // 16384
  int*   slot_of = (int*)(meta + (256 << 10));     // 16384
  int*   counts  = (int*)(meta + (320 << 10));     // 8
  int*   offsets = counts + 8;
  int*   cursor  = counts + 16;

  // 1. w1 [E][H][F] fp32 -> wT = w1t [E][F][H] bf16  (+ zero 24 meta words)
  transpose_cast_kernel<<<dim3(F_DIM / 64, H_DIM / 64, E_NUM), 256, 0, stream>>>(
      w1, wT, H_DIM, F_DIM, counts);
  // 2. router (+ x -> bf16, + per-block expert counts)
  router_kernel<<<256, 256, 0, stream>>>(x, rw, xb, top_e, top_p, counts);
  // 3. slot assignment (+ offsets publish, + slot_of for combine)
  assign_kernel<<<T_TOKENS / 256, 256, 0, stream>>>(top_e, top_p, counts, cursor,
                                                    map, gate, slot_of, offsets);
  // 4. fc1: hidden = gelu(x @ w1[e])  (256^2 half-K-unit ring kernel)
  moe_gemm256_kernel<H_DIM, F_DIM, true, true>
      <<<dim3(E_NUM, 32, F_DIM / 256), 512, 0, stream>>>(xb, wT, map, nullptr,
                                                         counts, offsets, hidden);
  // 5. w2 [E][F][H] fp32 -> wT = w2t [E][H][F] bf16 (wT free after fc1)
  transpose_cast_kernel<<<dim3(H_DIM / 64, F_DIM / 64, E_NUM), 256, 0, stream>>>(
      w2, wT, F_DIM, H_DIM, nullptr);
  // 6. fc2: y = gate * (hidden @ w2[e])  (same kernel, gate epilogue)
  moe_gemm256_kernel<F_DIM, H_DIM, false, false>
      <<<dim3(E_NUM, 32, H_DIM / 256), 512, 0, stream>>>(hidden, wT, nullptr, gate,
                                                         counts, offsets, y);
  // 7. combine two slots per token
  combine_kernel<<<T_TOKENS, 256, 0, stream>>>(y, slot_of, out);
}